// Round 5
// baseline (261.330 us; speedup 1.0000x reference)
//
#include <hip/hip_runtime.h>
#include <math.h>

#define NF 32
#define NN 4096
#define ND 64
#define NK 512

// loss = q_latent + 0.25 * e_latent = 1.25 * mean((q - x)^2)
#define LOSS_SCALE (1.25f / (float)(NF * NN * ND))
// rescue margin: rows with approx top-2 gap < TAU get exact fp32 re-argmin.
// 3-term split-bf16 score error: fp32-accum noise ~3e-5 + dropped lo*lo term
// <~1e-5; col-pack trunc e_t ~ 6e-5. Bound 4*e_a + 2*e_t ~ 2.6e-4 -> TAU 3e-4.
#define TAU 3e-4f

#define NPARTIAL (NF * NN * 4 / 256)   // 2048 gather blocks

typedef short bf16x8 __attribute__((ext_vector_type(8)));
typedef float f32x4 __attribute__((ext_vector_type(4)));

static __device__ __forceinline__ unsigned short f2bf_rne(float f) {
    unsigned int u = __float_as_uint(f);
    u += 0x7FFFu + ((u >> 16) & 1u);
    return (unsigned short)(u >> 16);
}
static __device__ __forceinline__ float bf2f(unsigned short h) {
    return __uint_as_float(((unsigned int)h) << 16);
}

// ---- DCE-blocking keep-alives (rule #17: ablation-via-skip DCEs upstream
// ops; these pin values in registers at zero instruction cost) ----
static __device__ __forceinline__ void keepf(float x) {
    asm volatile("" :: "v"(x));
}
static __device__ __forceinline__ void keep8(bf16x8 v) {
    union { bf16x8 b; f32x4 f; } u; u.b = v;
    asm volatile("" :: "v"(u.f[0]), "v"(u.f[1]), "v"(u.f[2]), "v"(u.f[3]));
}

// async global->LDS: 16B per lane, dest = wave-uniform base + lane*16
static __device__ __forceinline__ void gload_lds16(const void* g, void* l) {
    __builtin_amdgcn_global_load_lds(
        (const __attribute__((address_space(1))) unsigned int*)g,
        (__attribute__((address_space(3))) unsigned int*)l, 16, 0, 0);
}

// ---------------------------------------------------------------------------
// prep_w (fused): wt[f][k][d] = w[f][d][k]; wh/wl bf16 split; w2h = 0.5||w||^2
// via 8-lane shuffle reduce. thread per (f,k,dc): 512 blocks.
// ---------------------------------------------------------------------------
__global__ __launch_bounds__(256)
void vq_prep_w(const float* __restrict__ w, float* __restrict__ wt,
               unsigned short* __restrict__ wh, unsigned short* __restrict__ wl,
               float* __restrict__ w2h) {
    const int gid = blockIdx.x * 256 + threadIdx.x;   // [0, NF*NK*8)
    const int dc = gid & 7;
    const int k  = (gid >> 3) & (NK - 1);
    const int f  = gid >> 12;
    const float* __restrict__ wf = w + (size_t)f * ND * NK;
    const size_t rowo = ((size_t)f * NK + k) * ND + dc * 8;

    float v[8];
    unsigned short hh[8], ll[8];
    float s = 0.0f;
#pragma unroll
    for (int j = 0; j < 8; ++j) {
        v[j] = wf[(dc * 8 + j) * NK + k];
        s = fmaf(v[j], v[j], s);
        hh[j] = f2bf_rne(v[j]);
        ll[j] = f2bf_rne(v[j] - bf2f(hh[j]));
    }
    *(float4*)(wt + rowo)     = make_float4(v[0], v[1], v[2], v[3]);
    *(float4*)(wt + rowo + 4) = make_float4(v[4], v[5], v[6], v[7]);
    *(ushort4*)(wh + rowo)     = make_ushort4(hh[0], hh[1], hh[2], hh[3]);
    *(ushort4*)(wh + rowo + 4) = make_ushort4(hh[4], hh[5], hh[6], hh[7]);
    *(ushort4*)(wl + rowo)     = make_ushort4(ll[0], ll[1], ll[2], ll[3]);
    *(ushort4*)(wl + rowo + 4) = make_ushort4(ll[4], ll[5], ll[6], ll[7]);

    s += __shfl_xor(s, 1, 64);
    s += __shfl_xor(s, 2, 64);
    s += __shfl_xor(s, 4, 64);
    if (dc == 0) w2h[f * NK + k] = 0.5f * s;
}

// ---------------------------------------------------------------------------
// argmin ABLATION (R4 post-mortem: 4 structural theories falsified; per
// methodology, single-knockout ablation with per-dispatch rocprof timing).
//   V=0 FULL (production, runs LAST -> overwrites variant garbage)
//   V=1 noMIN   (stage+mfma, min/key chain stubbed w/ keepalive)
//   V=2 noSTAGE (no global loads/vmcnt; ds_reads read stale LDS)
//   V=3 noMFMA  (stage+ds_read+min on synthetic scores; frags kept alive)
// Base structure = R2 winner: block 4 waves x 32 rows, 256 cols (half K),
// dbuf-2 LDS staging, __syncthreads per supertile, grid 2048.
// ---------------------------------------------------------------------------
template <int V>
__global__ __launch_bounds__(256, 4)
void vq_argmin(const float* __restrict__ x_in,
               const unsigned short* __restrict__ wh,
               const unsigned short* __restrict__ wl,
               const float* __restrict__ w2h,
               float* __restrict__ pm1,
               float* __restrict__ pm2,
               float* __restrict__ pkm) {
    const int b2   = blockIdx.x;          // [0, 2048)
    const int h    = b2 & 1;              // column half
    const int b    = b2 >> 1;             // [0, 1024)
    const int j    = b >> 3;              // [0, 128)
    const int f    = (b & 7) * 4 + (j & 3);
    const int xt   = j >> 2;              // [0, 32)
    const int tid  = threadIdx.x;
    const int wave = tid >> 6;
    const int lane = tid & 63;
    const int lc   = lane & 15;
    const int q    = lane >> 4;
    const int n0   = xt * 128 + wave * 32;   // wave's private 32 rows

    __shared__ float w2s[256];                                // 1 KB
    __shared__ __align__(16) unsigned short bstage[2][4096];  // 2 x 8 KB

    w2s[tid] = w2h[f * NK + h * 256 + tid];

    // ---- A-frags: 32 rows' (-x), split to bf16 hi/lo in-register.
    bf16x8 ah[2][2], al[2][2];
    const float* __restrict__ xbase = x_in + ((size_t)f * NN + n0 + lc) * ND;
#pragma unroll
    for (int mt = 0; mt < 2; ++mt) {
#pragma unroll
        for (int s = 0; s < 2; ++s) {
            const float* p = xbase + mt * 16 * ND + s * 32 + q * 8;
            float4 u0 = *(const float4*)(p);
            float4 u1 = *(const float4*)(p + 4);
            float xv[8] = {-u0.x, -u0.y, -u0.z, -u0.w, -u1.x, -u1.y, -u1.z, -u1.w};
            bf16x8 hh, ll;
#pragma unroll
            for (int jj = 0; jj < 8; ++jj) {
                unsigned short hb = f2bf_rne(xv[jj]);
                unsigned short lb = f2bf_rne(xv[jj] - bf2f(hb));
                hh[jj] = (short)hb;
                ll[jj] = (short)lb;
            }
            ah[mt][s] = hh;
            al[mt][s] = ll;
        }
    }
    if (V == 3) {   // no MFMA consumer -> pin the prologue's output live
#pragma unroll
        for (int mt = 0; mt < 2; ++mt) {
#pragma unroll
            for (int s = 0; s < 2; ++s) { keep8(ah[mt][s]); keep8(al[mt][s]); }
        }
    }

    const unsigned short* __restrict__ whf = wh + (size_t)f * NK * ND;
    const unsigned short* __restrict__ wlf = wl + (size_t)f * NK * ND;

    float m1[8], m2[8], kmin[8];
#pragma unroll
    for (int ri = 0; ri < 8; ++ri) { m1[ri] = INFINITY; m2[ri] = INFINITY; kmin[ri] = INFINITY; }

    // ---- stage supertile st (32 cols of this half) into bstage[pb]:
    // 8 chunks of 1KB, 2 per wave. chunk c = tl*4 + sg*2 + (lo/hi).
#define STAGE(st, pb) do {                                                  \
    _Pragma("unroll")                                                       \
    for (int rep = 0; rep < 2; ++rep) {                                     \
        const int c  = wave * 2 + rep;                                      \
        const int tl = c >> 2;                                              \
        const int sg = (c >> 1) & 1;                                        \
        const unsigned short* src = ((c & 1) ? wlf : whf) +                 \
            (size_t)((h * 8 + (st)) * 32 + tl * 16 + lc) * ND + q * 8 + sg * 32; \
        gload_lds16(src, &bstage[pb][c * 512]);                             \
    }                                                                       \
} while (0)

    if (V != 2) STAGE(0, 0);

    for (int st = 0; st < 8; ++st) {
        __syncthreads();                 // drains this st's loads (vmcnt)
        if (V != 2 && st < 7) STAGE(st + 1, (st + 1) & 1);
        const unsigned short* __restrict__ bb = &bstage[st & 1][0];

#pragma unroll
        for (int tl = 0; tl < 2; ++tl) {
            const int col = h * 256 + st * 32 + tl * 16 + lc;
            bf16x8 bh0 = *(const bf16x8*)(bb + (tl * 4 + 0) * 512 + lane * 8);
            bf16x8 bl0 = *(const bf16x8*)(bb + (tl * 4 + 1) * 512 + lane * 8);
            bf16x8 bh1 = *(const bf16x8*)(bb + (tl * 4 + 2) * 512 + lane * 8);
            bf16x8 bl1 = *(const bf16x8*)(bb + (tl * 4 + 3) * 512 + lane * 8);
            if (V == 3) { keep8(bh0); keep8(bl0); keep8(bh1); keep8(bl1); }
            const float w2 = w2s[st * 32 + tl * 16 + lc];
#pragma unroll
            for (int mt = 0; mt < 2; ++mt) {
                f32x4 c = {w2, w2, w2, w2};
                if (V != 3) {
                    c = __builtin_amdgcn_mfma_f32_16x16x32_bf16(ah[mt][0], bh0, c, 0, 0, 0);
                    c = __builtin_amdgcn_mfma_f32_16x16x32_bf16(ah[mt][1], bh1, c, 0, 0, 0);
                    c = __builtin_amdgcn_mfma_f32_16x16x32_bf16(ah[mt][0], bl0, c, 0, 0, 0);
                    c = __builtin_amdgcn_mfma_f32_16x16x32_bf16(ah[mt][1], bl1, c, 0, 0, 0);
                    c = __builtin_amdgcn_mfma_f32_16x16x32_bf16(al[mt][0], bh0, c, 0, 0, 0);
                    c = __builtin_amdgcn_mfma_f32_16x16x32_bf16(al[mt][1], bh1, c, 0, 0, 0);
                }
#pragma unroll
                for (int r = 0; r < 4; ++r) {
                    const int ri = mt * 4 + r;
                    float sc = c[r];
                    if (V == 1) {        // min-chain knocked out; keep MFMA live
                        keepf(sc);
                        continue;
                    }
                    if (V == 3) {        // block const-fold of the min chain
                        asm volatile("" : "+v"(sc));
                    }
                    // idx channel: col packed into low 9 mantissa bits
                    const float key = __uint_as_float(
                        (__float_as_uint(sc) & 0xFFFFFE00u) | (unsigned int)col);
                    kmin[ri] = fminf(kmin[ri], key);
                    // flag channel: exact top-2
                    m2[ri] = __builtin_amdgcn_fmed3f(sc, m1[ri], m2[ri]);
                    m1[ri] = fminf(sc, m1[ri]);
                }
            }
        }
    }

    // ---- merge top-2 + kmin across the 16 lanes holding each row ----
#pragma unroll
    for (int ri = 0; ri < 8; ++ri) {
        float a1 = m1[ri], a2 = m2[ri], ak = kmin[ri];
#pragma unroll
        for (int off = 1; off < 16; off <<= 1) {
            const float b1 = __shfl_xor(a1, off, 64);
            const float b2 = __shfl_xor(a2, off, 64);
            const float bk = __shfl_xor(ak, off, 64);
            a2 = fminf(fminf(a2, b2), fmaxf(a1, b1));
            a1 = fminf(a1, b1);
            ak = fminf(ak, bk);
        }
        m1[ri] = a1; m2[ri] = a2; kmin[ri] = ak;
    }

    // ---- write this half's partials (merge happens in vq_rescue) ----
    if (lc == 0) {
        const size_t FN = (size_t)NF * NN;
#pragma unroll
        for (int mt = 0; mt < 2; ++mt) {
            const int g = f * NN + n0 + mt * 16 + q * 4;   // 4 consecutive rows
            float4 v1 = make_float4(m1[mt*4+0], m1[mt*4+1], m1[mt*4+2], m1[mt*4+3]);
            float4 v2 = make_float4(m2[mt*4+0], m2[mt*4+1], m2[mt*4+2], m2[mt*4+3]);
            float4 vk = make_float4(kmin[mt*4+0], kmin[mt*4+1], kmin[mt*4+2], kmin[mt*4+3]);
            *(float4*)(pm1 + h * FN + g) = v1;
            *(float4*)(pm2 + h * FN + g) = v2;
            *(float4*)(pkm + h * FN + g) = vk;
        }
    }
}

// ---------------------------------------------------------------------------
// rescue v2: (a) merge the two column-halves' partials -> keys + flag,
// (b) exact fp32 full-K argmin for flagged rows. One wave per 16-row group
// (8192 waves). Ballot the flags, full-wave rescan per set row. No atomics.
// grid: 2048 blocks.
// ---------------------------------------------------------------------------
__global__ __launch_bounds__(256)
void vq_rescue(const float* __restrict__ x_in, const float* __restrict__ wt,
               const float* __restrict__ w2h,
               const float* __restrict__ pm1, const float* __restrict__ pm2,
               const float* __restrict__ pkm,
               unsigned int* __restrict__ keys) {
    const int lane = threadIdx.x & 63;
    const int wid  = (blockIdx.x * 256 + threadIdx.x) >> 6;  // [0, 8192)
    const int base = wid * 16;
    const size_t FN = (size_t)NF * NN;

    int flag = 0;
    if (lane < 16) {
        const int g = base + lane;
        const float a1 = pm1[g], b1 = pm1[FN + g];
        const float a2 = pm2[g], b2 = pm2[FN + g];
        const float ka = pkm[g], kb = pkm[FN + g];
        const float m1f = fminf(a1, b1);
        const float m2f = fminf(fminf(a2, b2), fmaxf(a1, b1));
        const float kf  = fminf(ka, kb);
        keys[g] = __float_as_uint(kf) & 0x1FFu;
        flag = (m2f - m1f < TAU) ? 1 : 0;
    }
    unsigned long long m = __ballot(flag != 0);
    while (m) {
        const int r = __ffsll(m) - 1;
        m &= m - 1;
        const int g = base + r;
        const int f = g >> 12;                               // / NN
        const float* __restrict__ xr  = x_in + (size_t)g * ND;
        const float* __restrict__ wtf = wt + (size_t)f * NK * ND;
        unsigned long long best = 0xFFFFFFFFFFFFFFFFULL;
#pragma unroll 1
        for (int jj = 0; jj < 8; ++jj) {
            const int col = jj * 64 + lane;
            const float* __restrict__ wr = wtf + (size_t)col * ND;
            float t = w2h[f * NK + col];
#pragma unroll
            for (int d = 0; d < ND; d += 4) {
                float4 xv = *(const float4*)(xr + d);   // broadcast
                float4 wv = *(const float4*)(wr + d);
                t = fmaf(-xv.x, wv.x, t);
                t = fmaf(-xv.y, wv.y, t);
                t = fmaf(-xv.z, wv.z, t);
                t = fmaf(-xv.w, wv.w, t);
            }
            unsigned int u = __float_as_uint(t);
            u ^= (unsigned int)((int)u >> 31) | 0x80000000u;
            const unsigned long long key =
                ((unsigned long long)u << 32) | (unsigned int)col;
            best = key < best ? key : best;
        }
#pragma unroll
        for (int off = 32; off > 0; off >>= 1) {
            const unsigned long long o = __shfl_xor(best, off, 64);
            best = o < best ? o : best;
        }
        if (lane == 0) keys[g] = (unsigned int)(best & 0xFFFFFFFFULL);
    }
}

// ---------------------------------------------------------------------------
// gather: 4 threads per row; straight-through output. Per-block loss partial
// (plain store, no atomics). 2048 blocks.
// ---------------------------------------------------------------------------
__global__ __launch_bounds__(256)
void vq_gather(const float* __restrict__ x_in, const float* __restrict__ wt,
               const unsigned int* __restrict__ keys, float* __restrict__ out,
               float* __restrict__ partial) {
    const int gid = blockIdx.x * 256 + threadIdx.x;   // [0, NF*NN*4)
    const int row = gid >> 2;
    const int c   = (gid & 3) * 16;
    const int f   = row >> 12;
    const unsigned int k = keys[row];

    const float* __restrict__ q16 = wt + ((size_t)f * NK + k) * ND + c;
    const float* __restrict__ x16 = x_in + (size_t)row * ND + c;
    float* __restrict__ o16       = out + (size_t)row * ND + c;

    float lsum = 0.0f;
#pragma unroll
    for (int jj = 0; jj < 4; ++jj) {
        float4 qv = *(const float4*)(q16 + 4 * jj);
        float4 xv = *(const float4*)(x16 + 4 * jj);
        const float dx0 = qv.x - xv.x;
        const float dx1 = qv.y - xv.y;
        const float dx2 = qv.z - xv.z;
        const float dx3 = qv.w - xv.w;
        lsum = fmaf(dx0, dx0, lsum);
        lsum = fmaf(dx1, dx1, lsum);
        lsum = fmaf(dx2, dx2, lsum);
        lsum = fmaf(dx3, dx3, lsum);
        *(float4*)(o16 + 4 * jj) = qv;
    }

#pragma unroll
    for (int off = 32; off > 0; off >>= 1) {
        lsum += __shfl_down(lsum, off, 64);
    }
    __shared__ float wsum[4];
    if ((threadIdx.x & 63) == 0) wsum[threadIdx.x >> 6] = lsum;
    __syncthreads();
    if (threadIdx.x == 0) {
        partial[blockIdx.x] = wsum[0] + wsum[1] + wsum[2] + wsum[3];
    }
}

// ---------------------------------------------------------------------------
// loss_final: sum 2048 partials -> loss scalar. 1 block.
// ---------------------------------------------------------------------------
__global__ __launch_bounds__(256)
void vq_loss_final(const float* __restrict__ partial, float* __restrict__ loss) {
    float s = 0.0f;
    for (int i = threadIdx.x; i < NPARTIAL; i += 256) s += partial[i];
#pragma unroll
    for (int off = 32; off > 0; off >>= 1) s += __shfl_down(s, off, 64);
    __shared__ float wsum[4];
    if ((threadIdx.x & 63) == 0) wsum[threadIdx.x >> 6] = s;
    __syncthreads();
    if (threadIdx.x == 0) {
        *loss = (wsum[0] + wsum[1] + wsum[2] + wsum[3]) * LOSS_SCALE;
    }
}

extern "C" void kernel_launch(void* const* d_in, const int* in_sizes, int n_in,
                              void* d_out, int out_size, void* d_ws, size_t ws_size,
                              hipStream_t stream) {
    const float* x_in = (const float*)d_in[0];  // [F, N, D] fp32
    const float* w    = (const float*)d_in[1];  // [F, D, K] fp32
    float* out        = (float*)d_out;          // [F*N*D] output then [1] loss

    float* wt  = (float*)d_ws;                                   // 4 MB
    float* w2h = wt + (size_t)NF * NK * ND;                      // 64 KB
    unsigned short* wh = (unsigned short*)(w2h + NF * NK);       // 2 MB
    unsigned short* wl = wh + (size_t)NF * NK * ND;              // 2 MB
    unsigned int* keys = (unsigned int*)(wl + (size_t)NF * NK * ND); // 512 KB
    float* pm1 = (float*)(keys + (size_t)NF * NN);               // 1 MB (2 halves)
    float* pm2 = pm1 + (size_t)2 * NF * NN;                      // 1 MB
    float* pkm = pm2 + (size_t)2 * NF * NN;                      // 1 MB
    float* partial = pkm + (size_t)2 * NF * NN;                  // 8 KB

    float* loss_slot = out + (size_t)NF * NN * ND;

    vq_prep_w<<<NF * NK * 8 / 256, 256, 0, stream>>>(w, wt, wh, wl, w2h);

    // ---- ablation dispatches (write garbage into pm*; production V0 runs
    // last and overwrites every location) ----
    vq_argmin<1><<<NF * NN / 64, 256, 0, stream>>>(x_in, wh, wl, w2h, pm1, pm2, pkm);
    vq_argmin<2><<<NF * NN / 64, 256, 0, stream>>>(x_in, wh, wl, w2h, pm1, pm2, pkm);
    vq_argmin<3><<<NF * NN / 64, 256, 0, stream>>>(x_in, wh, wl, w2h, pm1, pm2, pkm);

    // ---- production ----
    vq_argmin<0><<<NF * NN / 64, 256, 0, stream>>>(x_in, wh, wl, w2h, pm1, pm2, pkm);

    vq_rescue<<<NF * NN / 16 / 4, 256, 0, stream>>>(x_in, wt, w2h, pm1, pm2, pkm, keys);

    vq_gather<<<NF * NN * 4 / 256, 256, 0, stream>>>(x_in, wt, keys, out, partial);

    vq_loss_final<<<1, 256, 0, stream>>>(partial, loss_slot);
}

// Round 6
// 253.154 us; speedup vs baseline: 1.0323x; 1.0323x over previous
//
#include <hip/hip_runtime.h>
#include <math.h>

#define NF 32
#define NN 4096
#define ND 64
#define NK 512

// loss = q_latent + 0.25 * e_latent = 1.25 * mean((q - x)^2)
#define LOSS_SCALE (1.25f / (float)(NF * NN * ND))
// rescue margin: rows with approx top-2 gap < TAU get exact fp32 re-argmin.
// 3-term split-bf16 score error: fp32-accum noise ~3e-5 + dropped lo*lo term
// <~1e-5; col-pack trunc e_t ~ 6e-5. Bound 4*e_a + 2*e_t ~ 2.6e-4 -> TAU 3e-4.
#define TAU 3e-4f

#define NPARTIAL (NF * NN * 4 / 256)   // 2048 gather blocks

typedef short bf16x8 __attribute__((ext_vector_type(8)));
typedef float f32x4 __attribute__((ext_vector_type(4)));

static __device__ __forceinline__ unsigned short f2bf_rne(float f) {
    unsigned int u = __float_as_uint(f);
    u += 0x7FFFu + ((u >> 16) & 1u);
    return (unsigned short)(u >> 16);
}
static __device__ __forceinline__ float bf2f(unsigned short h) {
    return __uint_as_float(((unsigned int)h) << 16);
}

// async global->LDS: 16B per lane, dest = wave-uniform base + lane*16
static __device__ __forceinline__ void gload_lds16(const void* g, void* l) {
    __builtin_amdgcn_global_load_lds(
        (const __attribute__((address_space(1))) unsigned int*)g,
        (__attribute__((address_space(3))) unsigned int*)l, 16, 0, 0);
}

// ---------------------------------------------------------------------------
// prep_w v2: LDS-transpose. Old version read w[f][d][k] with 8-lane-
// contiguous stride-2KB pattern (half-segment coalescing). New: block =
// (f, 64-col k-group); phase 1 reads a [64 d][64 k] tile with full-64B
// coalesced loads into LDS; phase 2 reads transposed, computes bf16 hi/lo
// split + 0.5||w||^2, writes wt/wh/wl fully coalesced. 256 blocks.
// ---------------------------------------------------------------------------
__global__ __launch_bounds__(256)
void vq_prep_w(const float* __restrict__ w, float* __restrict__ wt,
               unsigned short* __restrict__ wh, unsigned short* __restrict__ wl,
               float* __restrict__ w2h) {
    __shared__ float lds[64 * 65];        // +1 pad: transposed reads conflict-free
    const int t  = threadIdx.x;
    const int f  = blockIdx.x >> 3;
    const int k0 = (blockIdx.x & 7) * 64;
    const float* __restrict__ wf = w + (size_t)f * ND * NK;

    {   // phase 1: d = t>>2 (16 rows/wave), 4 float4 per thread
        const int d = t >> 2, qq = t & 3;
#pragma unroll
        for (int i = 0; i < 4; ++i) {
            const int c4 = qq + i * 4;    // float4 index within the 64-col row
            const float4 v = *(const float4*)(wf + (size_t)d * NK + k0 + c4 * 4);
            lds[d * 65 + c4 * 4 + 0] = v.x;
            lds[d * 65 + c4 * 4 + 1] = v.y;
            lds[d * 65 + c4 * 4 + 2] = v.z;
            lds[d * 65 + c4 * 4 + 3] = v.w;
        }
    }
    __syncthreads();

    // phase 2: thread owns (k = t>>2, d-range p*16..p*16+15)
    const int k = t >> 2, p = t & 3;
    float v[16];
    float s = 0.0f;
#pragma unroll
    for (int j = 0; j < 16; ++j) {
        v[j] = lds[(p * 16 + j) * 65 + k];
        s = fmaf(v[j], v[j], s);
    }
    s += __shfl_xor(s, 1, 64);            // 4 threads share one k
    s += __shfl_xor(s, 2, 64);
    if (p == 0) w2h[f * NK + k0 + k] = 0.5f * s;

    const size_t rowo = ((size_t)f * NK + k0 + k) * ND + p * 16;
    unsigned short hh[16], ll[16];
#pragma unroll
    for (int j = 0; j < 16; ++j) {
        hh[j] = f2bf_rne(v[j]);
        ll[j] = f2bf_rne(v[j] - bf2f(hh[j]));
    }
#pragma unroll
    for (int i = 0; i < 4; ++i) {
        *(float4*)(wt + rowo + i * 4) =
            make_float4(v[i*4+0], v[i*4+1], v[i*4+2], v[i*4+3]);
        *(ushort4*)(wh + rowo + i * 4) =
            make_ushort4(hh[i*4+0], hh[i*4+1], hh[i*4+2], hh[i*4+3]);
        *(ushort4*)(wl + rowo + i * 4) =
            make_ushort4(ll[i*4+0], ll[i*4+1], ll[i*4+2], ll[i*4+3]);
    }
}

// ---------------------------------------------------------------------------
// argmin v6: ONE-SHOT RESIDENT CODEBOOK, ZERO-BARRIER COMPUTE.
// R5 ablation (per-dispatch decode): no single knockout (min-chain, staging,
// MFMA) collapses the 44us -> the cost is the additive per-supertile phase
// structure itself (every component serialized once per barrier interval).
// Fix: the half-codebook (8 supertiles x 8KB = 64KB hi+lo) fits in LDS.
// Stage it ONCE (16 gload_lds16/thread), one __syncthreads, then compute
// 2 row-tiles x 128 rows with ZERO barriers / ZERO waitcnt in the stream:
// ds_read -> MFMA -> min chains free-run and overlap across 8 waves/CU.
// Block = (f, h, rg): 32 x 2 x 16 = 1024 blocks, 256 threads, 65KB LDS
// (2 blocks/CU). All 16 blocks of one (f,h) land on the same XCD
// (b%8 = fh%8) -> codebook reads are L2-local. Inner compute, fragment
// layout, TAU math, partial outputs identical to the passing R2 pipeline.
// ---------------------------------------------------------------------------
__global__ __launch_bounds__(256, 2)
void vq_argmin(const float* __restrict__ x_in,
               const unsigned short* __restrict__ wh,
               const unsigned short* __restrict__ wl,
               const float* __restrict__ w2h,
               float* __restrict__ pm1,
               float* __restrict__ pm2,
               float* __restrict__ pkm) {
    const int b    = blockIdx.x;          // [0, 1024)
    const int fh   = b & 63;
    const int f    = fh >> 1;
    const int h    = fh & 1;              // column half
    const int rg   = b >> 6;              // [0, 16): 256-row span
    const int tid  = threadIdx.x;
    const int wave = tid >> 6;
    const int lane = tid & 63;
    const int lc   = lane & 15;
    const int q    = lane >> 4;

    __shared__ float w2s[256];                                // 1 KB
    __shared__ __align__(16) unsigned short bstage[8][4096];  // 64 KB: whole half

    w2s[tid] = w2h[f * NK + h * 256 + tid];

    const unsigned short* __restrict__ whf = wh + (size_t)f * NK * ND;
    const unsigned short* __restrict__ wlf = wl + (size_t)f * NK * ND;

    // ---- one-shot stage: 8 supertiles x 8 chunks of 1KB (2 chunks/wave/st).
    // chunk c = tl*4 + sg*2 + (lo/hi); lane-linear dest (gload_lds req).
#pragma unroll
    for (int st = 0; st < 8; ++st) {
#pragma unroll
        for (int rep = 0; rep < 2; ++rep) {
            const int c  = wave * 2 + rep;
            const int tl = c >> 2;
            const int sg = (c >> 1) & 1;
            const unsigned short* src = ((c & 1) ? wlf : whf) +
                (size_t)((h * 8 + st) * 32 + tl * 16 + lc) * ND + q * 8 + sg * 32;
            gload_lds16(src, &bstage[st][c * 512]);
        }
    }
    __syncthreads();   // the only barrier: codebook resident from here on

    for (int rt = 0; rt < 2; ++rt) {
        const int n0 = rg * 256 + rt * 128 + wave * 32;   // wave's 32 rows

        // ---- A-frags: 32 rows' (-x), split to bf16 hi/lo in-register.
        bf16x8 ah[2][2], al[2][2];
        const float* __restrict__ xbase = x_in + ((size_t)f * NN + n0 + lc) * ND;
#pragma unroll
        for (int mt = 0; mt < 2; ++mt) {
#pragma unroll
            for (int s = 0; s < 2; ++s) {
                const float* p = xbase + mt * 16 * ND + s * 32 + q * 8;
                float4 u0 = *(const float4*)(p);
                float4 u1 = *(const float4*)(p + 4);
                float xv[8] = {-u0.x, -u0.y, -u0.z, -u0.w,
                               -u1.x, -u1.y, -u1.z, -u1.w};
                bf16x8 hh, ll;
#pragma unroll
                for (int jj = 0; jj < 8; ++jj) {
                    unsigned short hb = f2bf_rne(xv[jj]);
                    unsigned short lb = f2bf_rne(xv[jj] - bf2f(hb));
                    hh[jj] = (short)hb;
                    ll[jj] = (short)lb;
                }
                ah[mt][s] = hh;
                al[mt][s] = ll;
            }
        }

        float m1[8], m2[8], kmin[8];
#pragma unroll
        for (int ri = 0; ri < 8; ++ri) {
            m1[ri] = INFINITY; m2[ri] = INFINITY; kmin[ri] = INFINITY;
        }

#pragma unroll
        for (int st = 0; st < 8; ++st) {
            const unsigned short* __restrict__ bb = &bstage[st][0];
#pragma unroll
            for (int tl = 0; tl < 2; ++tl) {
                const int col = h * 256 + st * 32 + tl * 16 + lc;
                bf16x8 bh0 = *(const bf16x8*)(bb + (tl * 4 + 0) * 512 + lane * 8);
                bf16x8 bl0 = *(const bf16x8*)(bb + (tl * 4 + 1) * 512 + lane * 8);
                bf16x8 bh1 = *(const bf16x8*)(bb + (tl * 4 + 2) * 512 + lane * 8);
                bf16x8 bl1 = *(const bf16x8*)(bb + (tl * 4 + 3) * 512 + lane * 8);
                const float w2 = w2s[st * 32 + tl * 16 + lc];
#pragma unroll
                for (int mt = 0; mt < 2; ++mt) {
                    f32x4 c = {w2, w2, w2, w2};
                    c = __builtin_amdgcn_mfma_f32_16x16x32_bf16(ah[mt][0], bh0, c, 0, 0, 0);
                    c = __builtin_amdgcn_mfma_f32_16x16x32_bf16(ah[mt][1], bh1, c, 0, 0, 0);
                    c = __builtin_amdgcn_mfma_f32_16x16x32_bf16(ah[mt][0], bl0, c, 0, 0, 0);
                    c = __builtin_amdgcn_mfma_f32_16x16x32_bf16(ah[mt][1], bl1, c, 0, 0, 0);
                    c = __builtin_amdgcn_mfma_f32_16x16x32_bf16(al[mt][0], bh0, c, 0, 0, 0);
                    c = __builtin_amdgcn_mfma_f32_16x16x32_bf16(al[mt][1], bh1, c, 0, 0, 0);
#pragma unroll
                    for (int r = 0; r < 4; ++r) {
                        const int ri = mt * 4 + r;
                        const float sc = c[r];
                        // idx channel: col packed into low 9 mantissa bits
                        const float key = __uint_as_float(
                            (__float_as_uint(sc) & 0xFFFFFE00u) | (unsigned int)col);
                        kmin[ri] = fminf(kmin[ri], key);
                        // flag channel: exact top-2
                        m2[ri] = __builtin_amdgcn_fmed3f(sc, m1[ri], m2[ri]);
                        m1[ri] = fminf(sc, m1[ri]);
                    }
                }
            }
        }

        // ---- merge top-2 + kmin across the 16 lanes holding each row ----
#pragma unroll
        for (int ri = 0; ri < 8; ++ri) {
            float a1 = m1[ri], a2 = m2[ri], ak = kmin[ri];
#pragma unroll
            for (int off = 1; off < 16; off <<= 1) {
                const float b1 = __shfl_xor(a1, off, 64);
                const float b2 = __shfl_xor(a2, off, 64);
                const float bk = __shfl_xor(ak, off, 64);
                a2 = fminf(fminf(a2, b2), fmaxf(a1, b1));
                a1 = fminf(a1, b1);
                ak = fminf(ak, bk);
            }
            m1[ri] = a1; m2[ri] = a2; kmin[ri] = ak;
        }

        // ---- write this half's partials (merge happens in vq_rescue) ----
        if (lc == 0) {
            const size_t FN = (size_t)NF * NN;
#pragma unroll
            for (int mt = 0; mt < 2; ++mt) {
                const int g = f * NN + n0 + mt * 16 + q * 4;   // 4 consecutive rows
                float4 v1 = make_float4(m1[mt*4+0], m1[mt*4+1], m1[mt*4+2], m1[mt*4+3]);
                float4 v2 = make_float4(m2[mt*4+0], m2[mt*4+1], m2[mt*4+2], m2[mt*4+3]);
                float4 vk = make_float4(kmin[mt*4+0], kmin[mt*4+1], kmin[mt*4+2], kmin[mt*4+3]);
                *(float4*)(pm1 + h * FN + g) = v1;
                *(float4*)(pm2 + h * FN + g) = v2;
                *(float4*)(pkm + h * FN + g) = vk;
            }
        }
    }
}

// ---------------------------------------------------------------------------
// rescue v2: (a) merge the two column-halves' partials -> keys + flag,
// (b) exact fp32 full-K argmin for flagged rows. One wave per 16-row group
// (8192 waves). Ballot the flags, full-wave rescan per set row. No atomics.
// grid: 2048 blocks.
// ---------------------------------------------------------------------------
__global__ __launch_bounds__(256)
void vq_rescue(const float* __restrict__ x_in, const float* __restrict__ wt,
               const float* __restrict__ w2h,
               const float* __restrict__ pm1, const float* __restrict__ pm2,
               const float* __restrict__ pkm,
               unsigned int* __restrict__ keys) {
    const int lane = threadIdx.x & 63;
    const int wid  = (blockIdx.x * 256 + threadIdx.x) >> 6;  // [0, 8192)
    const int base = wid * 16;
    const size_t FN = (size_t)NF * NN;

    int flag = 0;
    if (lane < 16) {
        const int g = base + lane;
        const float a1 = pm1[g], b1 = pm1[FN + g];
        const float a2 = pm2[g], b2 = pm2[FN + g];
        const float ka = pkm[g], kb = pkm[FN + g];
        const float m1f = fminf(a1, b1);
        const float m2f = fminf(fminf(a2, b2), fmaxf(a1, b1));
        const float kf  = fminf(ka, kb);
        keys[g] = __float_as_uint(kf) & 0x1FFu;
        flag = (m2f - m1f < TAU) ? 1 : 0;
    }
    unsigned long long m = __ballot(flag != 0);
    while (m) {
        const int r = __ffsll(m) - 1;
        m &= m - 1;
        const int g = base + r;
        const int f = g >> 12;                               // / NN
        const float* __restrict__ xr  = x_in + (size_t)g * ND;
        const float* __restrict__ wtf = wt + (size_t)f * NK * ND;
        unsigned long long best = 0xFFFFFFFFFFFFFFFFULL;
#pragma unroll 1
        for (int jj = 0; jj < 8; ++jj) {
            const int col = jj * 64 + lane;
            const float* __restrict__ wr = wtf + (size_t)col * ND;
            float t = w2h[f * NK + col];
#pragma unroll
            for (int d = 0; d < ND; d += 4) {
                float4 xv = *(const float4*)(xr + d);   // broadcast
                float4 wv = *(const float4*)(wr + d);
                t = fmaf(-xv.x, wv.x, t);
                t = fmaf(-xv.y, wv.y, t);
                t = fmaf(-xv.z, wv.z, t);
                t = fmaf(-xv.w, wv.w, t);
            }
            unsigned int u = __float_as_uint(t);
            u ^= (unsigned int)((int)u >> 31) | 0x80000000u;
            const unsigned long long key =
                ((unsigned long long)u << 32) | (unsigned int)col;
            best = key < best ? key : best;
        }
#pragma unroll
        for (int off = 32; off > 0; off >>= 1) {
            const unsigned long long o = __shfl_xor(best, off, 64);
            best = o < best ? o : best;
        }
        if (lane == 0) keys[g] = (unsigned int)(best & 0xFFFFFFFFULL);
    }
}

// ---------------------------------------------------------------------------
// gather: 4 threads per row; straight-through output. Per-block loss partial
// (plain store, no atomics). 2048 blocks.
// ---------------------------------------------------------------------------
__global__ __launch_bounds__(256)
void vq_gather(const float* __restrict__ x_in, const float* __restrict__ wt,
               const unsigned int* __restrict__ keys, float* __restrict__ out,
               float* __restrict__ partial) {
    const int gid = blockIdx.x * 256 + threadIdx.x;   // [0, NF*NN*4)
    const int row = gid >> 2;
    const int c   = (gid & 3) * 16;
    const int f   = row >> 12;
    const unsigned int k = keys[row];

    const float* __restrict__ q16 = wt + ((size_t)f * NK + k) * ND + c;
    const float* __restrict__ x16 = x_in + (size_t)row * ND + c;
    float* __restrict__ o16       = out + (size_t)row * ND + c;

    float lsum = 0.0f;
#pragma unroll
    for (int jj = 0; jj < 4; ++jj) {
        float4 qv = *(const float4*)(q16 + 4 * jj);
        float4 xv = *(const float4*)(x16 + 4 * jj);
        const float dx0 = qv.x - xv.x;
        const float dx1 = qv.y - xv.y;
        const float dx2 = qv.z - xv.z;
        const float dx3 = qv.w - xv.w;
        lsum = fmaf(dx0, dx0, lsum);
        lsum = fmaf(dx1, dx1, lsum);
        lsum = fmaf(dx2, dx2, lsum);
        lsum = fmaf(dx3, dx3, lsum);
        *(float4*)(o16 + 4 * jj) = qv;
    }

#pragma unroll
    for (int off = 32; off > 0; off >>= 1) {
        lsum += __shfl_down(lsum, off, 64);
    }
    __shared__ float wsum[4];
    if ((threadIdx.x & 63) == 0) wsum[threadIdx.x >> 6] = lsum;
    __syncthreads();
    if (threadIdx.x == 0) {
        partial[blockIdx.x] = wsum[0] + wsum[1] + wsum[2] + wsum[3];
    }
}

// ---------------------------------------------------------------------------
// loss_final: sum 2048 partials -> loss scalar. 1 block.
// ---------------------------------------------------------------------------
__global__ __launch_bounds__(256)
void vq_loss_final(const float* __restrict__ partial, float* __restrict__ loss) {
    float s = 0.0f;
    for (int i = threadIdx.x; i < NPARTIAL; i += 256) s += partial[i];
#pragma unroll
    for (int off = 32; off > 0; off >>= 1) s += __shfl_down(s, off, 64);
    __shared__ float wsum[4];
    if ((threadIdx.x & 63) == 0) wsum[threadIdx.x >> 6] = s;
    __syncthreads();
    if (threadIdx.x == 0) {
        *loss = (wsum[0] + wsum[1] + wsum[2] + wsum[3]) * LOSS_SCALE;
    }
}

extern "C" void kernel_launch(void* const* d_in, const int* in_sizes, int n_in,
                              void* d_out, int out_size, void* d_ws, size_t ws_size,
                              hipStream_t stream) {
    const float* x_in = (const float*)d_in[0];  // [F, N, D] fp32
    const float* w    = (const float*)d_in[1];  // [F, D, K] fp32
    float* out        = (float*)d_out;          // [F*N*D] output then [1] loss

    float* wt  = (float*)d_ws;                                   // 4 MB
    float* w2h = wt + (size_t)NF * NK * ND;                      // 64 KB
    unsigned short* wh = (unsigned short*)(w2h + NF * NK);       // 2 MB
    unsigned short* wl = wh + (size_t)NF * NK * ND;              // 2 MB
    unsigned int* keys = (unsigned int*)(wl + (size_t)NF * NK * ND); // 512 KB
    float* pm1 = (float*)(keys + (size_t)NF * NN);               // 1 MB (2 halves)
    float* pm2 = pm1 + (size_t)2 * NF * NN;                      // 1 MB
    float* pkm = pm2 + (size_t)2 * NF * NN;                      // 1 MB
    float* partial = pkm + (size_t)2 * NF * NN;                  // 8 KB

    float* loss_slot = out + (size_t)NF * NN * ND;

    vq_prep_w<<<NF * 8, 256, 0, stream>>>(w, wt, wh, wl, w2h);

    vq_argmin<<<NF * 2 * 16, 256, 0, stream>>>(x_in, wh, wl, w2h, pm1, pm2, pkm);

    vq_rescue<<<NF * NN / 16 / 4, 256, 0, stream>>>(x_in, wt, w2h, pm1, pm2, pkm, keys);

    vq_gather<<<NF * NN * 4 / 256, 256, 0, stream>>>(x_in, wt, keys, out, partial);

    vq_loss_final<<<1, 256, 0, stream>>>(partial, loss_slot);
}

// Round 7
// 148.109 us; speedup vs baseline: 1.7644x; 1.7092x over previous
//
#include <hip/hip_runtime.h>
#include <math.h>

#define NF 32
#define NN 4096
#define ND 64
#define NK 512

// loss = q_latent + 0.25 * e_latent = 1.25 * mean((q - x)^2)
#define LOSS_SCALE (1.25f / (float)(NF * NN * ND))
// rescue margin: rows with approx top-2 gap < TAU get exact fp32 re-argmin.
// 3-term split-bf16 score error: fp32-accum noise ~3e-5 + dropped lo*lo term
// <~1e-5; col-pack trunc e_t ~ 6e-5. Bound 4*e_a + 2*e_t ~ 2.6e-4 -> TAU 3e-4.
#define TAU 3e-4f

typedef short bf16x8 __attribute__((ext_vector_type(8)));
typedef float f32x4 __attribute__((ext_vector_type(4)));

static __device__ __forceinline__ unsigned short f2bf_rne(float f) {
    unsigned int u = __float_as_uint(f);
    u += 0x7FFFu + ((u >> 16) & 1u);
    return (unsigned short)(u >> 16);
}
static __device__ __forceinline__ float bf2f(unsigned short h) {
    return __uint_as_float(((unsigned int)h) << 16);
}

// async global->LDS: 16B per lane, dest = wave-uniform base + lane*16
static __device__ __forceinline__ void gload_lds16(const void* g, void* l) {
    __builtin_amdgcn_global_load_lds(
        (const __attribute__((address_space(1))) unsigned int*)g,
        (__attribute__((address_space(3))) unsigned int*)l, 16, 0, 0);
}

// ---------------------------------------------------------------------------
// prep_w v2 (R6, passing): LDS-transpose for coalesced w reads. Block =
// (f, 64-col k-group); phase 1 reads [64 d][64 k] tile with full-64B
// coalesced loads into LDS; phase 2 reads transposed, computes bf16 hi/lo
// split + 0.5||w||^2, writes wt/wh/wl coalesced. Also zeroes the loss slot
// (block 0) for the fused argmin's atomicAdd. 256 blocks.
// ---------------------------------------------------------------------------
__global__ __launch_bounds__(256)
void vq_prep_w(const float* __restrict__ w, float* __restrict__ wt,
               unsigned short* __restrict__ wh, unsigned short* __restrict__ wl,
               float* __restrict__ w2h, float* __restrict__ loss_slot) {
    __shared__ float lds[64 * 65];        // +1 pad: transposed reads conflict-free
    const int t  = threadIdx.x;
    const int f  = blockIdx.x >> 3;
    const int k0 = (blockIdx.x & 7) * 64;
    const float* __restrict__ wf = w + (size_t)f * ND * NK;

    if (blockIdx.x == 0 && t == 0) *loss_slot = 0.0f;

    {   // phase 1: d = t>>2 (16 rows/wave), 4 float4 per thread
        const int d = t >> 2, qq = t & 3;
#pragma unroll
        for (int i = 0; i < 4; ++i) {
            const int c4 = qq + i * 4;    // float4 index within the 64-col row
            const float4 v = *(const float4*)(wf + (size_t)d * NK + k0 + c4 * 4);
            lds[d * 65 + c4 * 4 + 0] = v.x;
            lds[d * 65 + c4 * 4 + 1] = v.y;
            lds[d * 65 + c4 * 4 + 2] = v.z;
            lds[d * 65 + c4 * 4 + 3] = v.w;
        }
    }
    __syncthreads();

    // phase 2: thread owns (k = t>>2, d-range p*16..p*16+15)
    const int k = t >> 2, p = t & 3;
    float v[16];
    float s = 0.0f;
#pragma unroll
    for (int j = 0; j < 16; ++j) {
        v[j] = lds[(p * 16 + j) * 65 + k];
        s = fmaf(v[j], v[j], s);
    }
    s += __shfl_xor(s, 1, 64);            // 4 threads share one k
    s += __shfl_xor(s, 2, 64);
    if (p == 0) w2h[f * NK + k0 + k] = 0.5f * s;

    const size_t rowo = ((size_t)f * NK + k0 + k) * ND + p * 16;
    unsigned short hh[16], ll[16];
#pragma unroll
    for (int j = 0; j < 16; ++j) {
        hh[j] = f2bf_rne(v[j]);
        ll[j] = f2bf_rne(v[j] - bf2f(hh[j]));
    }
#pragma unroll
    for (int i = 0; i < 4; ++i) {
        *(float4*)(wt + rowo + i * 4) =
            make_float4(v[i*4+0], v[i*4+1], v[i*4+2], v[i*4+3]);
        *(ushort4*)(wh + rowo + i * 4) =
            make_ushort4(hh[i*4+0], hh[i*4+1], hh[i*4+2], hh[i*4+3]);
        *(ushort4*)(wl + rowo + i * 4) =
            make_ushort4(ll[i*4+0], ll[i*4+1], ll[i*4+2], ll[i*4+3]);
    }
}

// ---------------------------------------------------------------------------
// argmin FUSED (v7): R0 full-K main loop (proven 44-46us, 56-60 VGPR) +
// in-kernel rescue + gather + loss. Motivation (R5/R6 decomposition): the
// non-argmin side of the 5-kernel pipeline is a constant ~118us -- larger
// than argmin itself -- dominated by inter-kernel gaps, keys/pm HBM round
// trips and 3 extra kernels. Full-K per block => min state is block-local:
//   phase 1: 16-supertile dbuf MFMA loop (unchanged math, 3-term split)
//   phase 2: lane-merge -> keys+flags into LDS (no HBM)
//   phase 3: wave-local exact fp32 rescan of flagged rows (w2 from LDS,
//            wt rows L2-hot, x row broadcast-read)
//   phase 4: block gather: out rows + (q-x)^2 partial -> one atomicAdd
// Pipeline collapses 5 kernels -> 2; keys/pm1/pm2/pkm/partial deleted.
// ---------------------------------------------------------------------------
__global__ __launch_bounds__(256, 4)
void vq_argmin(const float* __restrict__ x_in,
               const unsigned short* __restrict__ wh,
               const unsigned short* __restrict__ wl,
               const float* __restrict__ wt,
               const float* __restrict__ w2h,
               float* __restrict__ out,
               float* __restrict__ loss_slot) {
    const int b    = blockIdx.x;          // [0, 1024)
    const int j    = b >> 3;              // [0, 128)
    const int f    = (b & 7) * 4 + (j & 3);
    const int xt   = j >> 2;              // [0, 32)
    const int tid  = threadIdx.x;
    const int wave = tid >> 6;
    const int lane = tid & 63;
    const int lc   = lane & 15;
    const int q    = lane >> 4;
    const int n0   = xt * 128 + wave * 32;   // wave's private 32 rows
    const int g0b  = f * NN + xt * 128;      // block's global row base

    __shared__ float w2s[NK];                                 // 2 KB
    __shared__ __align__(16) unsigned short bstage[2][4096];  // 2 x 8 KB
    __shared__ unsigned int lds_key[128];                     // 512 B
    __shared__ unsigned char lds_flag[128];                   // 128 B

    for (int t = tid; t < NK; t += 256) w2s[t] = w2h[f * NK + t];

    // ---- A-frags: 32 rows' (-x), split to bf16 hi/lo in-register.
    bf16x8 ah[2][2], al[2][2];
    const float* __restrict__ xbase = x_in + ((size_t)f * NN + n0 + lc) * ND;
#pragma unroll
    for (int mt = 0; mt < 2; ++mt) {
#pragma unroll
        for (int s = 0; s < 2; ++s) {
            const float* p = xbase + mt * 16 * ND + s * 32 + q * 8;
            float4 u0 = *(const float4*)(p);
            float4 u1 = *(const float4*)(p + 4);
            float xv[8] = {-u0.x, -u0.y, -u0.z, -u0.w, -u1.x, -u1.y, -u1.z, -u1.w};
            bf16x8 hh, ll;
#pragma unroll
            for (int jj = 0; jj < 8; ++jj) {
                unsigned short hb = f2bf_rne(xv[jj]);
                unsigned short lb = f2bf_rne(xv[jj] - bf2f(hb));
                hh[jj] = (short)hb;
                ll[jj] = (short)lb;
            }
            ah[mt][s] = hh;
            al[mt][s] = ll;
        }
    }

    const unsigned short* __restrict__ whf = wh + (size_t)f * NK * ND;
    const unsigned short* __restrict__ wlf = wl + (size_t)f * NK * ND;

    float m1[8], m2[8], kmin[8];
#pragma unroll
    for (int ri = 0; ri < 8; ++ri) { m1[ri] = INFINITY; m2[ri] = INFINITY; kmin[ri] = INFINITY; }

    // ---- stage supertile st (32 cols) into bstage[pb]: 8 chunks of 1KB,
    // 2 per wave. chunk c = tl*4 + sg*2 + (lo/hi). lane-linear dest.
#define STAGE(st, pb) do {                                                  \
    _Pragma("unroll")                                                       \
    for (int rep = 0; rep < 2; ++rep) {                                     \
        const int c  = wave * 2 + rep;                                      \
        const int tl = c >> 2;                                              \
        const int sg = (c >> 1) & 1;                                        \
        const unsigned short* src = ((c & 1) ? wlf : whf) +                 \
            (size_t)((st) * 32 + tl * 16 + lc) * ND + q * 8 + sg * 32;      \
        gload_lds16(src, &bstage[pb][c * 512]);                             \
    }                                                                       \
} while (0)

    STAGE(0, 0);

    for (int st = 0; st < 16; ++st) {
        __syncthreads();                 // drains this st's loads (vmcnt)
        if (st < 15) STAGE(st + 1, (st + 1) & 1);
        const unsigned short* __restrict__ bb = &bstage[st & 1][0];

#pragma unroll
        for (int tl = 0; tl < 2; ++tl) {
            const int col = st * 32 + tl * 16 + lc;
            bf16x8 bh0 = *(const bf16x8*)(bb + (tl * 4 + 0) * 512 + lane * 8);
            bf16x8 bl0 = *(const bf16x8*)(bb + (tl * 4 + 1) * 512 + lane * 8);
            bf16x8 bh1 = *(const bf16x8*)(bb + (tl * 4 + 2) * 512 + lane * 8);
            bf16x8 bl1 = *(const bf16x8*)(bb + (tl * 4 + 3) * 512 + lane * 8);
            const float w2 = w2s[col];
#pragma unroll
            for (int mt = 0; mt < 2; ++mt) {
                f32x4 c = {w2, w2, w2, w2};
                c = __builtin_amdgcn_mfma_f32_16x16x32_bf16(ah[mt][0], bh0, c, 0, 0, 0);
                c = __builtin_amdgcn_mfma_f32_16x16x32_bf16(ah[mt][1], bh1, c, 0, 0, 0);
                c = __builtin_amdgcn_mfma_f32_16x16x32_bf16(ah[mt][0], bl0, c, 0, 0, 0);
                c = __builtin_amdgcn_mfma_f32_16x16x32_bf16(ah[mt][1], bl1, c, 0, 0, 0);
                c = __builtin_amdgcn_mfma_f32_16x16x32_bf16(al[mt][0], bh0, c, 0, 0, 0);
                c = __builtin_amdgcn_mfma_f32_16x16x32_bf16(al[mt][1], bh1, c, 0, 0, 0);
#pragma unroll
                for (int r = 0; r < 4; ++r) {
                    const int ri = mt * 4 + r;
                    const float sc = c[r];
                    // idx channel: col packed into low 9 mantissa bits
                    const float key = __uint_as_float(
                        (__float_as_uint(sc) & 0xFFFFFE00u) | (unsigned int)col);
                    kmin[ri] = fminf(kmin[ri], key);
                    // flag channel: exact top-2
                    m2[ri] = __builtin_amdgcn_fmed3f(sc, m1[ri], m2[ri]);
                    m1[ri] = fminf(sc, m1[ri]);
                }
            }
        }
    }

    // ---- phase 2: merge across the 16 lanes holding each row ----
#pragma unroll
    for (int ri = 0; ri < 8; ++ri) {
        float a1 = m1[ri], a2 = m2[ri], ak = kmin[ri];
#pragma unroll
        for (int off = 1; off < 16; off <<= 1) {
            const float b1 = __shfl_xor(a1, off, 64);
            const float b2 = __shfl_xor(a2, off, 64);
            const float bk = __shfl_xor(ak, off, 64);
            a2 = fminf(fminf(a2, b2), fmaxf(a1, b1));
            a1 = fminf(a1, b1);
            ak = fminf(ak, bk);
        }
        m1[ri] = a1; m2[ri] = a2; kmin[ri] = ak;
    }

    if (lc == 0) {
#pragma unroll
        for (int mt = 0; mt < 2; ++mt) {
#pragma unroll
            for (int r = 0; r < 4; ++r) {
                const int ri = mt * 4 + r;
                const int lr = wave * 32 + mt * 16 + q * 4 + r;  // block-local row
                lds_key[lr]  = __float_as_uint(kmin[ri]) & 0x1FFu;
                lds_flag[lr] = (m2[ri] - m1[ri] < TAU) ? 1 : 0;
            }
        }
    }
    __syncthreads();

    // ---- phase 3: wave-local exact rescue of flagged rows ----
    {
        const int lr32 = wave * 32 + (lane & 31);
        const int fl = (lane < 32) ? lds_flag[lr32] : 0;
        unsigned long long mm = __ballot(fl != 0);
        const float* __restrict__ wtf = wt + (size_t)f * NK * ND;
        while (mm) {
            const int r = __ffsll(mm) - 1;
            mm &= mm - 1;
            const int grow = g0b + wave * 32 + r;
            const float* __restrict__ xr = x_in + (size_t)grow * ND;
            unsigned long long best = 0xFFFFFFFFFFFFFFFFULL;
#pragma unroll 1
            for (int jj = 0; jj < 8; ++jj) {
                const int col = jj * 64 + lane;
                const float* __restrict__ wr = wtf + (size_t)col * ND;
                float t = w2s[col];
#pragma unroll
                for (int d = 0; d < ND; d += 4) {
                    float4 xv = *(const float4*)(xr + d);   // broadcast
                    float4 wv = *(const float4*)(wr + d);
                    t = fmaf(-xv.x, wv.x, t);
                    t = fmaf(-xv.y, wv.y, t);
                    t = fmaf(-xv.z, wv.z, t);
                    t = fmaf(-xv.w, wv.w, t);
                }
                unsigned int u = __float_as_uint(t);
                u ^= (unsigned int)((int)u >> 31) | 0x80000000u;
                const unsigned long long key =
                    ((unsigned long long)u << 32) | (unsigned int)col;
                best = key < best ? key : best;
            }
#pragma unroll
            for (int off = 32; off > 0; off >>= 1) {
                const unsigned long long o = __shfl_xor(best, off, 64);
                best = o < best ? o : best;
            }
            if (lane == 0) lds_key[wave * 32 + r] = (unsigned int)(best & 0x1FFu);
        }
    }
    __syncthreads();

    // ---- phase 4: gather + loss. 2 threads per row (32 floats each);
    // reads/writes fully contiguous across the block's 128 rows. ----
    {
        const int row_l = tid >> 1;
        const int part  = tid & 1;
        const int grow  = g0b + row_l;
        const unsigned int k = lds_key[row_l];
        const float* __restrict__ q32 = wt + ((size_t)f * NK + k) * ND + part * 32;
        const float* __restrict__ x32 = x_in + (size_t)grow * ND + part * 32;
        float* __restrict__ o32       = out + (size_t)grow * ND + part * 32;

        float lsum = 0.0f;
#pragma unroll
        for (int jj = 0; jj < 8; ++jj) {
            float4 qv = *(const float4*)(q32 + 4 * jj);
            float4 xv = *(const float4*)(x32 + 4 * jj);
            const float dx0 = qv.x - xv.x;
            const float dx1 = qv.y - xv.y;
            const float dx2 = qv.z - xv.z;
            const float dx3 = qv.w - xv.w;
            lsum = fmaf(dx0, dx0, lsum);
            lsum = fmaf(dx1, dx1, lsum);
            lsum = fmaf(dx2, dx2, lsum);
            lsum = fmaf(dx3, dx3, lsum);
            *(float4*)(o32 + 4 * jj) = qv;
        }

#pragma unroll
        for (int off = 32; off > 0; off >>= 1) {
            lsum += __shfl_down(lsum, off, 64);
        }
        __shared__ float wsum[4];
        if ((tid & 63) == 0) wsum[tid >> 6] = lsum;
        __syncthreads();
        if (tid == 0) {
            atomicAdd(loss_slot,
                      (wsum[0] + wsum[1] + wsum[2] + wsum[3]) * LOSS_SCALE);
        }
    }
}

extern "C" void kernel_launch(void* const* d_in, const int* in_sizes, int n_in,
                              void* d_out, int out_size, void* d_ws, size_t ws_size,
                              hipStream_t stream) {
    const float* x_in = (const float*)d_in[0];  // [F, N, D] fp32
    const float* w    = (const float*)d_in[1];  // [F, D, K] fp32
    float* out        = (float*)d_out;          // [F*N*D] output then [1] loss

    float* wt  = (float*)d_ws;                                   // 4 MB
    float* w2h = wt + (size_t)NF * NK * ND;                      // 64 KB
    unsigned short* wh = (unsigned short*)(w2h + NF * NK);       // 2 MB
    unsigned short* wl = wh + (size_t)NF * NK * ND;              // 2 MB

    float* loss_slot = out + (size_t)NF * NN * ND;

    vq_prep_w<<<NF * 8, 256, 0, stream>>>(w, wt, wh, wl, w2h, loss_slot);

    vq_argmin<<<NF * NN / 128, 256, 0, stream>>>(x_in, wh, wl, wt, w2h,
                                                 out, loss_slot);
}